// Round 8
// baseline (506.668 us; speedup 1.0000x reference)
//
#include <hip/hip_runtime.h>
#include <stdint.h>

// Problem constants
#define NB 2
#define NS 2048
#define NE 1024
#define NH 16
#define ND 64

typedef __attribute__((ext_vector_type(8))) short short8;
typedef __attribute__((ext_vector_type(4))) float f4;
typedef __attribute__((ext_vector_type(16))) float f16v;
typedef __attribute__((ext_vector_type(4))) unsigned short us4;

static __device__ __forceinline__ unsigned short bf16_rne(float x) {
  uint32_t u = __builtin_bit_cast(uint32_t, x);
  u += 0x7fffu + ((u >> 16) & 1u);
  return (unsigned short)(u >> 16);
}
static __device__ __forceinline__ float bf16_f32(unsigned short h) {
  uint32_t u = ((uint32_t)h) << 16;
  return __builtin_bit_cast(float, u);
}

// JAX threefry2x32, key = (0, 42), 20 rounds.
static __device__ __forceinline__ void threefry42(uint32_t x0, uint32_t x1,
                                                  uint32_t& o0, uint32_t& o1) {
  const uint32_t ks0 = 0u, ks1 = 42u;
  const uint32_t ks2 = 0u ^ 42u ^ 0x1BD11BDAu;
  x0 += ks0; x1 += ks1;
#define TF4(a,b,c,d) \
  x0 += x1; x1 = __builtin_rotateleft32(x1, a); x1 ^= x0; \
  x0 += x1; x1 = __builtin_rotateleft32(x1, b); x1 ^= x0; \
  x0 += x1; x1 = __builtin_rotateleft32(x1, c); x1 ^= x0; \
  x0 += x1; x1 = __builtin_rotateleft32(x1, d); x1 ^= x0;
  TF4(13,15,26,6)  x0 += ks1; x1 += ks2 + 1u;
  TF4(17,29,16,24) x0 += ks2; x1 += ks0 + 2u;
  TF4(13,15,26,6)  x0 += ks0; x1 += ks1 + 3u;
  TF4(17,29,16,24) x0 += ks1; x1 += ks2 + 4u;
  TF4(13,15,26,6)  x0 += ks2; x1 += ks0 + 5u;
#undef TF4
  o0 = x0; o1 = x1;
}

// async global->LDS 16B/lane.
static __device__ __forceinline__ void gl2lds16(const void* g, void* l) {
  __builtin_amdgcn_global_load_lds(
      (const __attribute__((address_space(1))) uint32_t*)g,
      (__attribute__((address_space(3))) uint32_t*)l, 16, 0, 0);
}

// ---------------- kernel 0: split fp32 -> bf16 hi/lo ----------------
__global__ void k_split(const float* __restrict__ x, const float* __restrict__ qw,
                        const float* __restrict__ ow,
                        unsigned short* __restrict__ xh, unsigned short* __restrict__ xl,
                        unsigned short* __restrict__ wh, unsigned short* __restrict__ wl,
                        unsigned short* __restrict__ woh) {
  for (uint32_t i = blockIdx.x * 256u + threadIdx.x; i < 8388608u; i += gridDim.x * 256u) {
    if (i < 4194304u) {
      float v = x[i];
      unsigned short hi = bf16_rne(v);
      xh[i] = hi;
      xl[i] = bf16_rne(v - bf16_f32(hi));
    } else if (i < 7340032u) {
      uint32_t j = i - 4194304u;
      float v = qw[j];
      unsigned short hi = bf16_rne(v);
      wh[j] = hi;
      wl[j] = bf16_rne(v - bf16_f32(hi));
    } else {
      uint32_t j = i - 7340032u;
      woh[j] = bf16_rne(ow[j]);
    }
  }
}

// ---------------- kernel 1: QKV GEMM, 32x32 split-bf16 MFMA -----------------
// Round-8: + XCD-chunked block swizzle (T1). Default round-robin id%8->XCD
// makes every XCD touch ALL 32 A-panels and all 24 B-panels -> each kt-slice
// fetched 8x from HBM (~229MB). Chunked: XCD x gets contiguous wg range
// [x*96, x*96+96) = 4 bm-rows x 24 bn -> per-XCD A set 2MB (L2-resident),
// A fetched once per XCD-chunk -> HBM ~115MB. Bijective (768 % 8 == 0).
// (a) 32x32x16 MFMAs (R7-verified); (b) chunk-rotation LDS swizzle with
// pre-swizzled GLOBAL source column (LDS linear, gl2lds-compatible).
__global__ __launch_bounds__(256) void k_qkv(
    const unsigned short* __restrict__ xh, const unsigned short* __restrict__ xl,
    const unsigned short* __restrict__ wh, const unsigned short* __restrict__ wl,
    const float* __restrict__ qkv_b,
    unsigned short* __restrict__ Qh, unsigned short* __restrict__ Ql,
    unsigned short* __restrict__ Kh, unsigned short* __restrict__ Kl,
    unsigned short* __restrict__ Vt) {
  __shared__ unsigned short SM[16384];  // 32KB, carved; reused by V transpose
  unsigned short* Ah = SM;
  unsigned short* Al = SM + 4096;
  unsigned short* Bh = SM + 8192;
  unsigned short* Bl = SM + 12288;
  const int tid = threadIdx.x;
  const int lane = tid & 63, wid = tid >> 6;
  const int wm = wid >> 1, wn = wid & 1;
  // XCD-chunked swizzle: xcd = id&7 (default round-robin), contiguous chunk of
  // 96 work-groups per XCD; wg -> (bn, bm) with bn fastest.
  const int id = blockIdx.x;
  const int wg = (id & 7) * 96 + (id >> 3);
  const int bn = wg % 24, bm = wg / 24;
  const bool isV = (bn >= 16);
  const int l31 = lane & 31, h = lane >> 5;
  const int ldrow = lane >> 2;
  // swizzled global source chunk (see header comment)
  const int ldk = (((lane & 3) - ((lane >> 3) & 3)) & 3) * 8;
  // read-side physical-chunk rotation base: (row>>1)&3 == (l31>>1)&3
  const int rot = (l31 >> 1) & 3;

  f16v acc[2][2];
#pragma unroll
  for (int a = 0; a < 2; ++a)
#pragma unroll
    for (int b = 0; b < 2; ++b)
      acc[a][b] = (f16v){0.f,0.f,0.f,0.f,0.f,0.f,0.f,0.f,0.f,0.f,0.f,0.f,0.f,0.f,0.f,0.f};

  for (int kt = 0; kt < 32; ++kt) {
    const int k0 = kt * 32;
    __syncthreads();
#pragma unroll
    for (int r = 0; r < 2; ++r) {
      const int c = wid + r * 4;
      const int grow = c * 16 + ldrow;
      const size_t ao = (size_t)(bm * 128 + grow) * 1024 + k0 + ldk;
      const size_t bo = (size_t)(bn * 128 + grow) * 1024 + k0 + ldk;
      const int lo = c * 512 + lane * 8;
      gl2lds16(xh + ao, &Ah[lo]);
      gl2lds16(wh + bo, &Bh[lo]);
      if (!isV) {
        gl2lds16(xl + ao, &Al[lo]);
        gl2lds16(wl + bo, &Bl[lo]);
      }
    }
    __syncthreads();

#pragma unroll
    for (int ks = 0; ks < 2; ++ks) {
      const int lc = ks * 2 + h;          // logical 16B chunk within the row
      const int pcs = ((lc + rot) & 3) * 8;
      short8 af[2], bf_[2], alf[2], blf[2];
#pragma unroll
      for (int t = 0; t < 2; ++t) {
        const int arow = wm * 64 + t * 32 + l31;
        const int brow = wn * 64 + t * 32 + l31;
        af[t]  = *(const short8*)&Ah[arow * 32 + pcs];
        bf_[t] = *(const short8*)&Bh[brow * 32 + pcs];
        if (!isV) {
          alf[t] = *(const short8*)&Al[arow * 32 + pcs];
          blf[t] = *(const short8*)&Bl[brow * 32 + pcs];
        }
      }
      if (isV) {
#pragma unroll
        for (int tm = 0; tm < 2; ++tm)
#pragma unroll
          for (int tn = 0; tn < 2; ++tn)
            acc[tm][tn] = __builtin_amdgcn_mfma_f32_32x32x16_bf16(af[tm], bf_[tn], acc[tm][tn], 0, 0, 0);
      } else {
#pragma unroll
        for (int tm = 0; tm < 2; ++tm)
#pragma unroll
          for (int tn = 0; tn < 2; ++tn) {
            acc[tm][tn] = __builtin_amdgcn_mfma_f32_32x32x16_bf16(af[tm], bf_[tn], acc[tm][tn], 0, 0, 0);
            acc[tm][tn] = __builtin_amdgcn_mfma_f32_32x32x16_bf16(af[tm], blf[tn], acc[tm][tn], 0, 0, 0);
            acc[tm][tn] = __builtin_amdgcn_mfma_f32_32x32x16_bf16(alf[tm], bf_[tn], acc[tm][tn], 0, 0, 0);
          }
      }
    }
  }

  if (!isV) {
    // epilogue Q/K: hi/lo bf16 [bh][s][d]; C-layout col=l31, row=(a&3)+8*(a>>2)+4h
#pragma unroll
    for (int tm = 0; tm < 2; ++tm) {
#pragma unroll
      for (int tn = 0; tn < 2; ++tn) {
        const int j = bn * 128 + wn * 64 + tn * 32 + l31;
        const float bias = qkv_b[j];
        const int which = j >> 10;
        const int rem = j & 1023;
        const int hd = rem >> 6, d = rem & 63;
#pragma unroll
        for (int a = 0; a < 16; ++a) {
          const int m_local = wm * 64 + tm * 32 + (a & 3) + 8 * (a >> 2) + 4 * h;
          const int i = bm * 128 + m_local;
          const int b = i >> 11, s = i & 2047;
          const size_t off = (((size_t)(b * 16 + hd)) * 2048 + (size_t)s) * 64 + d;
          const float v = acc[tm][tn][a] + bias;
          const unsigned short hi = bf16_rne(v);
          const unsigned short lo = bf16_rne(v - bf16_f32(hi));
          if (which == 0) { Qh[off] = hi; Ql[off] = lo; }
          else            { Kh[off] = hi; Kl[off] = lo; }
        }
      }
    }
  } else {
    // epilogue V: LDS transpose [d_local 128][s_local 128], then coalesced Vt
    __syncthreads();
#pragma unroll
    for (int tm = 0; tm < 2; ++tm) {
#pragma unroll
      for (int tn = 0; tn < 2; ++tn) {
        const int d_local = wn * 64 + tn * 32 + l31;
        const float bias = qkv_b[bn * 128 + d_local];
#pragma unroll
        for (int a = 0; a < 16; ++a) {
          const int s_local = wm * 64 + tm * 32 + (a & 3) + 8 * (a >> 2) + 4 * h;
          SM[d_local * 128 + s_local] = bf16_rne(acc[tm][tn][a] + bias);
        }
      }
    }
    __syncthreads();
    const int b = (bm * 128) >> 11;
    const int s0 = (bm * 128) & 2047;
    const int h2 = (bn - 16) * 2;
#pragma unroll
    for (int it = 0; it < 8; ++it) {
      const int chunk = it * 256 + tid;
      const int dr = chunk >> 4;
      const int sc = (chunk & 15) * 8;
      const short8 v = *(const short8*)&SM[dr * 128 + sc];
      const int bh = b * 16 + h2 + (dr >> 6);
      const int d = dr & 63;
      *(short8*)&Vt[((size_t)bh * 64 + d) * 2048 + s0 + sc] = v;
    }
  }
}

// ---------------- kernel 2: MFMA flash attention + exact threefry sampling ----
// EXACT round-0 kernel (proven best: 324-327us, no spills, 0 conflicts).
// R1-R6 bracketed it from every direction (occupancy up/down, LDS traffic /3,
// MFMA shape, phase order) - all neutral or worse. k_attn is pinned at its
// threefry integer-ALU issue floor (~283us + MFMA/barrier residual); closed.
// Deliberately NOT swizzled (not BW-bound; don't perturb the proven kernel).
__global__ __launch_bounds__(256) void k_attn(
    const unsigned short* __restrict__ Qh, const unsigned short* __restrict__ Ql,
    const unsigned short* __restrict__ Khg, const unsigned short* __restrict__ Klg,
    const unsigned short* __restrict__ Vtg, unsigned short* __restrict__ AO) {
  __shared__ unsigned short Ksh[4096], Ksl[4096], Vs[8192], Pm[4096];
  const int tid = threadIdx.x;
  const int lane = tid & 63, w = tid >> 6;
  const int quad = lane >> 4, c16 = lane & 15;
  const int q0 = blockIdx.x * 64;
  const int bh = blockIdx.y;
  const size_t base = (size_t)bh * (size_t)(2048 * 64);

  // Q fragments for this wave's 16 rows (A-operand: m=c16, k=quad*8+j)
  const size_t qoff = base + (size_t)(q0 + w * 16 + c16) * 64 + quad * 8;
  const short8 qh0 = *(const short8*)&Qh[qoff];
  const short8 qh1 = *(const short8*)&Qh[qoff + 32];
  const short8 ql0 = *(const short8*)&Ql[qoff];
  const short8 ql1 = *(const short8*)&Ql[qoff + 32];

  // flat-index base for threefry: f = bh*2^22 + q*2048 + k
  const uint32_t fb = (uint32_t)bh * 4194304u +
                      (uint32_t)(q0 + w * 16 + quad * 4) * 2048u + (uint32_t)c16;

  // swizzled staging indices: LDS chunk c holds global chunk ((c&7) - (c>>3)) & 7
  const int c0 = tid, r0 = c0 >> 3, g0 = ((c0 & 7) - r0) & 7;
  const int c1 = tid + 256, r1 = c1 >> 3, g1 = ((c1 & 7) - r1) & 7;

  f4 oacc[4];
#pragma unroll
  for (int s = 0; s < 4; ++s) { f4 z = {0.f, 0.f, 0.f, 0.f}; oacc[s] = z; }

  auto stage = [&](int kb, int vbuf) {
    const size_t koff = base + (size_t)kb * 64;
    gl2lds16(Khg + koff + r0 * 64 + g0 * 8, &Ksh[c0 * 8]);
    gl2lds16(Klg + koff + r0 * 64 + g0 * 8, &Ksl[c0 * 8]);
    gl2lds16(Vtg + base + (size_t)r0 * 2048 + kb + g0 * 8, &Vs[vbuf * 4096 + c0 * 8]);
    gl2lds16(Khg + koff + r1 * 64 + g1 * 8, &Ksh[c1 * 8]);
    gl2lds16(Klg + koff + r1 * 64 + g1 * 8, &Ksl[c1 * 8]);
    gl2lds16(Vtg + base + (size_t)r1 * 2048 + kb + g1 * 8, &Vs[vbuf * 4096 + c1 * 8]);
  };

  stage(0, 0);

  for (int kt = 0; kt < 32; ++kt) {
    const int kb = kt * 64;
    const int vb = (kt & 1) * 4096;
    __syncthreads();  // tile kb staged; all waves past previous compute

    // S = Q.K^T split-bf16 3 passes; K fragments read inline (swizzled rows)
    f4 sacc[4];
#pragma unroll
    for (int sub = 0; sub < 4; ++sub) {
      const int rK = sub * 16 + c16;
      const int sA = ((quad + rK) & 7) * 8;
      const int sB = ((quad + 4 + rK) & 7) * 8;
      const short8 kh0 = *(const short8*)&Ksh[rK * 64 + sA];
      const short8 kh1 = *(const short8*)&Ksh[rK * 64 + sB];
      const short8 kl0 = *(const short8*)&Ksl[rK * 64 + sA];
      const short8 kl1 = *(const short8*)&Ksl[rK * 64 + sB];
      f4 s = {0.f, 0.f, 0.f, 0.f};
      s = __builtin_amdgcn_mfma_f32_16x16x32_bf16(qh0, kh0, s, 0, 0, 0);
      s = __builtin_amdgcn_mfma_f32_16x16x32_bf16(qh1, kh1, s, 0, 0, 0);
      s = __builtin_amdgcn_mfma_f32_16x16x32_bf16(qh0, kl0, s, 0, 0, 0);
      s = __builtin_amdgcn_mfma_f32_16x16x32_bf16(qh1, kl1, s, 0, 0, 0);
      s = __builtin_amdgcn_mfma_f32_16x16x32_bf16(ql0, kh0, s, 0, 0, 0);
      s = __builtin_amdgcn_mfma_f32_16x16x32_bf16(ql1, kh1, s, 0, 0, 0);
      sacc[sub] = s;
    }
    __syncthreads();  // K tile fully consumed by all waves (V[vb] untouched)
    if (kt < 31) stage(kb + 64, (kt & 1) ^ 1);  // lands during threefry below

    // threefry + sigmoid sample -> swizzled Pm (0x3F80 / 0 bf16 mask)
    // u < p  <=>  m*(1+e) < 2^23, m = (float)((o0^o1)>>9), e = 2^(s*-log2e/8)
#pragma unroll
    for (int sub = 0; sub < 4; ++sub) {
      const int qP = sub * 2 + (c16 >> 3);
#pragma unroll
      for (int rr = 0; rr < 4; ++rr) {
        const uint32_t f = fb + (uint32_t)(rr * 2048) + (uint32_t)(kb + sub * 16);
        uint32_t o0, o1;
        threefry42(0u, f, o0, o1);
        const float m = (float)((o0 ^ o1) >> 9);
        const float e = __builtin_amdgcn_exp2f(sacc[sub][rr] * -0.18033688f);
        const int rP = w * 16 + quad * 4 + rr;
        const int addr = rP * 64 + (((qP + rP) & 7) * 8) + (c16 & 7);
        Pm[addr] = (fmaf(m, e, m) < 8388608.0f) ? 0x3F80u : 0u;
      }
    }

    // O += P.V — P rows wave-private (lgkmcnt orders write->read); V inline
    const int rp = w * 16 + c16;
    const short8 pa0 = *(const short8*)&Pm[rp * 64 + ((quad + rp) & 7) * 8];
    const short8 pa1 = *(const short8*)&Pm[rp * 64 + ((quad + 4 + rp) & 7) * 8];
#pragma unroll
    for (int sub = 0; sub < 4; ++sub) {
      const int rV = sub * 16 + c16;
      const short8 vv0 = *(const short8*)&Vs[vb + rV * 64 + ((quad + rV) & 7) * 8];
      const short8 vv1 = *(const short8*)&Vs[vb + rV * 64 + ((quad + 4 + rV) & 7) * 8];
      oacc[sub] = __builtin_amdgcn_mfma_f32_16x16x32_bf16(pa0, vv0, oacc[sub], 0, 0, 0);
      oacc[sub] = __builtin_amdgcn_mfma_f32_16x16x32_bf16(pa1, vv1, oacc[sub], 0, 0, 0);
    }
  }

  // epilogue: AO[b*2048+s][h*64+d] bf16; C-layout row=quad*4+r (q), col=c16 (d)
  const int b = bh >> 4, hh = bh & 15;
#pragma unroll
  for (int sub = 0; sub < 4; ++sub)
#pragma unroll
    for (int r = 0; r < 4; ++r) {
      const int srow = b * 2048 + q0 + w * 16 + quad * 4 + r;
      AO[(size_t)srow * 1024 + hh * 64 + sub * 16 + c16] = bf16_rne(oacc[sub][r]);
    }
}

// ---------------- kernel 3: output projection, 32x32 bf16 MFMA ---------------
// Round-8: + XCD-chunked swizzle (32 wgs/XCD = 4 bm x 8 bn: per-XCD panel set
// A 1MB + B 2MB fits L2 -> HBM 80MB -> 24MB). Bijective (256 % 8 == 0).
__global__ __launch_bounds__(256) void k_out(
    const unsigned short* __restrict__ A, const unsigned short* __restrict__ Bw,
    const float* __restrict__ out_b, float* __restrict__ out) {
  __shared__ unsigned short As[128 * 32], Bs[128 * 32];
  const int tid = threadIdx.x;
  const int lane = tid & 63, wid = tid >> 6;
  const int wm = wid >> 1, wn = wid & 1;
  const int id = blockIdx.x;
  const int wg = (id & 7) * 32 + (id >> 3);
  const int bn = wg & 7, bm = wg >> 3;
  const int l31 = lane & 31, h = lane >> 5;
  const int ldrow = lane >> 2;
  const int ldk = (((lane & 3) - ((lane >> 3) & 3)) & 3) * 8;
  const int rot = (l31 >> 1) & 3;

  f16v acc[2][2];
#pragma unroll
  for (int a = 0; a < 2; ++a)
#pragma unroll
    for (int b = 0; b < 2; ++b)
      acc[a][b] = (f16v){0.f,0.f,0.f,0.f,0.f,0.f,0.f,0.f,0.f,0.f,0.f,0.f,0.f,0.f,0.f,0.f};

  for (int kt = 0; kt < 32; ++kt) {
    const int k0 = kt * 32;
    __syncthreads();
#pragma unroll
    for (int r = 0; r < 2; ++r) {
      const int c = wid + r * 4;
      const int grow = c * 16 + ldrow;
      const size_t ao = (size_t)(bm * 128 + grow) * 1024 + k0 + ldk;
      const size_t bo = (size_t)(bn * 128 + grow) * 1024 + k0 + ldk;
      const int lo = c * 512 + lane * 8;
      gl2lds16(A + ao, &As[lo]);
      gl2lds16(Bw + bo, &Bs[lo]);
    }
    __syncthreads();

#pragma unroll
    for (int ks = 0; ks < 2; ++ks) {
      const int lc = ks * 2 + h;
      const int pcs = ((lc + rot) & 3) * 8;
      short8 af[2], bf_[2];
#pragma unroll
      for (int t = 0; t < 2; ++t) {
        af[t]  = *(const short8*)&As[(wm * 64 + t * 32 + l31) * 32 + pcs];
        bf_[t] = *(const short8*)&Bs[(wn * 64 + t * 32 + l31) * 32 + pcs];
      }
#pragma unroll
      for (int tm = 0; tm < 2; ++tm)
#pragma unroll
        for (int tn = 0; tn < 2; ++tn)
          acc[tm][tn] = __builtin_amdgcn_mfma_f32_32x32x16_bf16(af[tm], bf_[tn], acc[tm][tn], 0, 0, 0);
    }
  }

#pragma unroll
  for (int tm = 0; tm < 2; ++tm) {
#pragma unroll
    for (int tn = 0; tn < 2; ++tn) {
      const int j = bn * 128 + wn * 64 + tn * 32 + l31;
      const float bias = out_b[j];
#pragma unroll
      for (int a = 0; a < 16; ++a) {
        const int i = bm * 128 + wm * 64 + tm * 32 + (a & 3) + 8 * (a >> 2) + 4 * h;
        out[(size_t)i * 1024 + j] = acc[tm][tn][a] + bias;
      }
    }
  }
}

extern "C" void kernel_launch(void* const* d_in, const int* in_sizes, int n_in,
                              void* d_out, int out_size, void* d_ws, size_t ws_size,
                              hipStream_t stream) {
  const float* x     = (const float*)d_in[0];
  const float* qkv_w = (const float*)d_in[3];
  const float* qkv_b = (const float*)d_in[4];
  const float* out_w = (const float*)d_in[5];
  const float* out_b = (const float*)d_in[6];
  float* out = (float*)d_out;

  // workspace carve (ushorts); AO aliases xh (xh dead after k_qkv)
  unsigned short* xh  = (unsigned short*)d_ws;        // 4194304
  unsigned short* xl  = xh + 4194304;                 // 4194304
  unsigned short* wh  = xl + 4194304;                 // 3145728
  unsigned short* wl  = wh + 3145728;                 // 3145728
  unsigned short* woh = wl + 3145728;                 // 1048576
  unsigned short* Vt  = woh + 1048576;                // 4194304
  unsigned short* Qh  = Vt + 4194304;                 // 4194304
  unsigned short* Ql  = Qh + 4194304;                 // 4194304
  unsigned short* Kh  = Ql + 4194304;                 // 4194304
  unsigned short* Kl  = Kh + 4194304;                 // 4194304
  unsigned short* AO  = xh;                           // alias

  k_split<<<8192, 256, 0, stream>>>(x, qkv_w, out_w, xh, xl, wh, wl, woh);
  k_qkv<<<768, 256, 0, stream>>>(xh, xl, wh, wl, qkv_b, Qh, Ql, Kh, Kl, Vt);
  k_attn<<<dim3(32, 32), 256, 0, stream>>>(Qh, Ql, Kh, Kl, Vt, AO);
  k_out<<<256, 256, 0, stream>>>(AO, woh, out_b, out);
}

// Round 9
// 502.690 us; speedup vs baseline: 1.0079x; 1.0079x over previous
//
#include <hip/hip_runtime.h>
#include <stdint.h>

// Problem constants
#define NB 2
#define NS 2048
#define NE 1024
#define NH 16
#define ND 64

typedef __attribute__((ext_vector_type(8))) short short8;
typedef __attribute__((ext_vector_type(4))) float f4;
typedef __attribute__((ext_vector_type(16))) float f16v;
typedef __attribute__((ext_vector_type(4))) unsigned short us4;

static __device__ __forceinline__ unsigned short bf16_rne(float x) {
  uint32_t u = __builtin_bit_cast(uint32_t, x);
  u += 0x7fffu + ((u >> 16) & 1u);
  return (unsigned short)(u >> 16);
}
static __device__ __forceinline__ float bf16_f32(unsigned short h) {
  uint32_t u = ((uint32_t)h) << 16;
  return __builtin_bit_cast(float, u);
}

// JAX threefry2x32, key = (0, 42), 20 rounds.
static __device__ __forceinline__ void threefry42(uint32_t x0, uint32_t x1,
                                                  uint32_t& o0, uint32_t& o1) {
  const uint32_t ks0 = 0u, ks1 = 42u;
  const uint32_t ks2 = 0u ^ 42u ^ 0x1BD11BDAu;
  x0 += ks0; x1 += ks1;
#define TF4(a,b,c,d) \
  x0 += x1; x1 = __builtin_rotateleft32(x1, a); x1 ^= x0; \
  x0 += x1; x1 = __builtin_rotateleft32(x1, b); x1 ^= x0; \
  x0 += x1; x1 = __builtin_rotateleft32(x1, c); x1 ^= x0; \
  x0 += x1; x1 = __builtin_rotateleft32(x1, d); x1 ^= x0;
  TF4(13,15,26,6)  x0 += ks1; x1 += ks2 + 1u;
  TF4(17,29,16,24) x0 += ks2; x1 += ks0 + 2u;
  TF4(13,15,26,6)  x0 += ks0; x1 += ks1 + 3u;
  TF4(17,29,16,24) x0 += ks1; x1 += ks2 + 4u;
  TF4(13,15,26,6)  x0 += ks2; x1 += ks0 + 5u;
#undef TF4
  o0 = x0; o1 = x1;
}

// async global->LDS 16B/lane.
static __device__ __forceinline__ void gl2lds16(const void* g, void* l) {
  __builtin_amdgcn_global_load_lds(
      (const __attribute__((address_space(1))) uint32_t*)g,
      (__attribute__((address_space(3))) uint32_t*)l, 16, 0, 0);
}

// ---------------- kernel 0: split fp32 -> bf16 hi/lo ----------------
__global__ void k_split(const float* __restrict__ x, const float* __restrict__ qw,
                        const float* __restrict__ ow,
                        unsigned short* __restrict__ xh, unsigned short* __restrict__ xl,
                        unsigned short* __restrict__ wh, unsigned short* __restrict__ wl,
                        unsigned short* __restrict__ woh) {
  for (uint32_t i = blockIdx.x * 256u + threadIdx.x; i < 8388608u; i += gridDim.x * 256u) {
    if (i < 4194304u) {
      float v = x[i];
      unsigned short hi = bf16_rne(v);
      xh[i] = hi;
      xl[i] = bf16_rne(v - bf16_f32(hi));
    } else if (i < 7340032u) {
      uint32_t j = i - 4194304u;
      float v = qw[j];
      unsigned short hi = bf16_rne(v);
      wh[j] = hi;
      wl[j] = bf16_rne(v - bf16_f32(hi));
    } else {
      uint32_t j = i - 7340032u;
      woh[j] = bf16_rne(ow[j]);
    }
  }
}

// ---------------- kernel 1: QKV GEMM, 32x32 split-bf16 MFMA -----------------
// Round-9: DOUBLE-BUFFERED staging. The old loop was barrier -> issue loads
// for THIS tile -> barrier(vmcnt0 drain) -> compute: every kt ate the full
// L2/L3 latency as a dead stall. Now: barrier -> stage(kt+1, other buf) ->
// compute(kt); the next barrier both drains the prefetch (landed under
// compute) and protects buffer reuse. LDS 64KB (2 x {Ah,Al,Bh,Bl}) -> 2
// blocks/CU; latency hidden in-wave (k_attn's proven pattern).
// XCD swizzle REVERTED (R8: L3 absorbs cross-XCD reuse; swizzle was -4us).
// Keeps R7's 32x32x16 MFMAs + chunk-rotation LDS swizzle (pre-swizzled
// global source column; LDS linear, gl2lds-compatible).
__global__ __launch_bounds__(256) void k_qkv(
    const unsigned short* __restrict__ xh, const unsigned short* __restrict__ xl,
    const unsigned short* __restrict__ wh, const unsigned short* __restrict__ wl,
    const float* __restrict__ qkv_b,
    unsigned short* __restrict__ Qh, unsigned short* __restrict__ Ql,
    unsigned short* __restrict__ Kh, unsigned short* __restrict__ Kl,
    unsigned short* __restrict__ Vt) {
  __shared__ unsigned short SM[32768];  // 64KB: 2 buffers x {Ah,Al,Bh,Bl}
  const int tid = threadIdx.x;
  const int lane = tid & 63, wid = tid >> 6;
  const int wm = wid >> 1, wn = wid & 1;
  const int bn = blockIdx.x, bm = blockIdx.y;
  const bool isV = (bn >= 16);
  const int l31 = lane & 31, h = lane >> 5;
  const int ldrow = lane >> 2;
  // pre-swizzled global source chunk
  const int ldk = (((lane & 3) - ((lane >> 3) & 3)) & 3) * 8;
  // read-side physical-chunk rotation base
  const int rot = (l31 >> 1) & 3;

  f16v acc[2][2];
#pragma unroll
  for (int a = 0; a < 2; ++a)
#pragma unroll
    for (int b = 0; b < 2; ++b)
      acc[a][b] = (f16v){0.f,0.f,0.f,0.f,0.f,0.f,0.f,0.f,0.f,0.f,0.f,0.f,0.f,0.f,0.f,0.f};

  auto stage = [&](int kt, int buf) {
    const int k0 = kt * 32;
    unsigned short* Ah = SM + buf * 16384;
#pragma unroll
    for (int r = 0; r < 2; ++r) {
      const int c = wid + r * 4;
      const int grow = c * 16 + ldrow;
      const size_t ao = (size_t)(bm * 128 + grow) * 1024 + k0 + ldk;
      const size_t bo = (size_t)(bn * 128 + grow) * 1024 + k0 + ldk;
      const int lo = c * 512 + lane * 8;
      gl2lds16(xh + ao, &Ah[lo]);
      gl2lds16(wh + bo, &Ah[8192 + lo]);
      if (!isV) {
        gl2lds16(xl + ao, &Ah[4096 + lo]);
        gl2lds16(wl + bo, &Ah[12288 + lo]);
      }
    }
  };

  stage(0, 0);

  for (int kt = 0; kt < 32; ++kt) {
    const int cb = kt & 1;
    __syncthreads();  // drains prefetch of tile kt; all waves done with buf cb^1
    if (kt < 31) stage(kt + 1, cb ^ 1);  // lands under compute below

    const unsigned short* Ah = SM + cb * 16384;
    const unsigned short* Al = Ah + 4096;
    const unsigned short* Bh = Ah + 8192;
    const unsigned short* Bl = Ah + 12288;
#pragma unroll
    for (int ks = 0; ks < 2; ++ks) {
      const int lc = ks * 2 + h;          // logical 16B chunk within the row
      const int pcs = ((lc + rot) & 3) * 8;
      short8 af[2], bf_[2], alf[2], blf[2];
#pragma unroll
      for (int t = 0; t < 2; ++t) {
        const int arow = wm * 64 + t * 32 + l31;
        const int brow = wn * 64 + t * 32 + l31;
        af[t]  = *(const short8*)&Ah[arow * 32 + pcs];
        bf_[t] = *(const short8*)&Bh[brow * 32 + pcs];
        if (!isV) {
          alf[t] = *(const short8*)&Al[arow * 32 + pcs];
          blf[t] = *(const short8*)&Bl[brow * 32 + pcs];
        }
      }
      if (isV) {
#pragma unroll
        for (int tm = 0; tm < 2; ++tm)
#pragma unroll
          for (int tn = 0; tn < 2; ++tn)
            acc[tm][tn] = __builtin_amdgcn_mfma_f32_32x32x16_bf16(af[tm], bf_[tn], acc[tm][tn], 0, 0, 0);
      } else {
#pragma unroll
        for (int tm = 0; tm < 2; ++tm)
#pragma unroll
          for (int tn = 0; tn < 2; ++tn) {
            acc[tm][tn] = __builtin_amdgcn_mfma_f32_32x32x16_bf16(af[tm], bf_[tn], acc[tm][tn], 0, 0, 0);
            acc[tm][tn] = __builtin_amdgcn_mfma_f32_32x32x16_bf16(af[tm], blf[tn], acc[tm][tn], 0, 0, 0);
            acc[tm][tn] = __builtin_amdgcn_mfma_f32_32x32x16_bf16(alf[tm], bf_[tn], acc[tm][tn], 0, 0, 0);
          }
      }
    }
  }

  if (!isV) {
    // epilogue Q/K: hi/lo bf16 [bh][s][d]; C-layout col=l31, row=(a&3)+8*(a>>2)+4h
#pragma unroll
    for (int tm = 0; tm < 2; ++tm) {
#pragma unroll
      for (int tn = 0; tn < 2; ++tn) {
        const int j = bn * 128 + wn * 64 + tn * 32 + l31;
        const float bias = qkv_b[j];
        const int which = j >> 10;
        const int rem = j & 1023;
        const int hd = rem >> 6, d = rem & 63;
#pragma unroll
        for (int a = 0; a < 16; ++a) {
          const int m_local = wm * 64 + tm * 32 + (a & 3) + 8 * (a >> 2) + 4 * h;
          const int i = bm * 128 + m_local;
          const int b = i >> 11, s = i & 2047;
          const size_t off = (((size_t)(b * 16 + hd)) * 2048 + (size_t)s) * 64 + d;
          const float v = acc[tm][tn][a] + bias;
          const unsigned short hi = bf16_rne(v);
          const unsigned short lo = bf16_rne(v - bf16_f32(hi));
          if (which == 0) { Qh[off] = hi; Ql[off] = lo; }
          else            { Kh[off] = hi; Kl[off] = lo; }
        }
      }
    }
  } else {
    // epilogue V: LDS transpose [d_local 128][s_local 128], then coalesced Vt
    __syncthreads();
#pragma unroll
    for (int tm = 0; tm < 2; ++tm) {
#pragma unroll
      for (int tn = 0; tn < 2; ++tn) {
        const int d_local = wn * 64 + tn * 32 + l31;
        const float bias = qkv_b[bn * 128 + d_local];
#pragma unroll
        for (int a = 0; a < 16; ++a) {
          const int s_local = wm * 64 + tm * 32 + (a & 3) + 8 * (a >> 2) + 4 * h;
          SM[d_local * 128 + s_local] = bf16_rne(acc[tm][tn][a] + bias);
        }
      }
    }
    __syncthreads();
    const int b = (bm * 128) >> 11;
    const int s0 = (bm * 128) & 2047;
    const int h2 = (bn - 16) * 2;
#pragma unroll
    for (int it = 0; it < 8; ++it) {
      const int chunk = it * 256 + tid;
      const int dr = chunk >> 4;
      const int sc = (chunk & 15) * 8;
      const short8 v = *(const short8*)&SM[dr * 128 + sc];
      const int bh = b * 16 + h2 + (dr >> 6);
      const int d = dr & 63;
      *(short8*)&Vt[((size_t)bh * 64 + d) * 2048 + s0 + sc] = v;
    }
  }
}

// ---------------- kernel 2: MFMA flash attention + exact threefry sampling ----
// EXACT round-0 kernel (proven best: 324-327us, no spills, 0 conflicts).
// R1-R6 bracketed it from every direction (occupancy up/down, LDS traffic /3,
// MFMA shape, phase order) - all neutral or worse. k_attn is pinned at its
// threefry integer-ALU issue floor (~283us + MFMA/barrier residual); closed.
__global__ __launch_bounds__(256) void k_attn(
    const unsigned short* __restrict__ Qh, const unsigned short* __restrict__ Ql,
    const unsigned short* __restrict__ Khg, const unsigned short* __restrict__ Klg,
    const unsigned short* __restrict__ Vtg, unsigned short* __restrict__ AO) {
  __shared__ unsigned short Ksh[4096], Ksl[4096], Vs[8192], Pm[4096];
  const int tid = threadIdx.x;
  const int lane = tid & 63, w = tid >> 6;
  const int quad = lane >> 4, c16 = lane & 15;
  const int q0 = blockIdx.x * 64;
  const int bh = blockIdx.y;
  const size_t base = (size_t)bh * (size_t)(2048 * 64);

  // Q fragments for this wave's 16 rows (A-operand: m=c16, k=quad*8+j)
  const size_t qoff = base + (size_t)(q0 + w * 16 + c16) * 64 + quad * 8;
  const short8 qh0 = *(const short8*)&Qh[qoff];
  const short8 qh1 = *(const short8*)&Qh[qoff + 32];
  const short8 ql0 = *(const short8*)&Ql[qoff];
  const short8 ql1 = *(const short8*)&Ql[qoff + 32];

  // flat-index base for threefry: f = bh*2^22 + q*2048 + k
  const uint32_t fb = (uint32_t)bh * 4194304u +
                      (uint32_t)(q0 + w * 16 + quad * 4) * 2048u + (uint32_t)c16;

  // swizzled staging indices: LDS chunk c holds global chunk ((c&7) - (c>>3)) & 7
  const int c0 = tid, r0 = c0 >> 3, g0 = ((c0 & 7) - r0) & 7;
  const int c1 = tid + 256, r1 = c1 >> 3, g1 = ((c1 & 7) - r1) & 7;

  f4 oacc[4];
#pragma unroll
  for (int s = 0; s < 4; ++s) { f4 z = {0.f, 0.f, 0.f, 0.f}; oacc[s] = z; }

  auto stage = [&](int kb, int vbuf) {
    const size_t koff = base + (size_t)kb * 64;
    gl2lds16(Khg + koff + r0 * 64 + g0 * 8, &Ksh[c0 * 8]);
    gl2lds16(Klg + koff + r0 * 64 + g0 * 8, &Ksl[c0 * 8]);
    gl2lds16(Vtg + base + (size_t)r0 * 2048 + kb + g0 * 8, &Vs[vbuf * 4096 + c0 * 8]);
    gl2lds16(Khg + koff + r1 * 64 + g1 * 8, &Ksh[c1 * 8]);
    gl2lds16(Klg + koff + r1 * 64 + g1 * 8, &Ksl[c1 * 8]);
    gl2lds16(Vtg + base + (size_t)r1 * 2048 + kb + g1 * 8, &Vs[vbuf * 4096 + c1 * 8]);
  };

  stage(0, 0);

  for (int kt = 0; kt < 32; ++kt) {
    const int kb = kt * 64;
    const int vb = (kt & 1) * 4096;
    __syncthreads();  // tile kb staged; all waves past previous compute

    // S = Q.K^T split-bf16 3 passes; K fragments read inline (swizzled rows)
    f4 sacc[4];
#pragma unroll
    for (int sub = 0; sub < 4; ++sub) {
      const int rK = sub * 16 + c16;
      const int sA = ((quad + rK) & 7) * 8;
      const int sB = ((quad + 4 + rK) & 7) * 8;
      const short8 kh0 = *(const short8*)&Ksh[rK * 64 + sA];
      const short8 kh1 = *(const short8*)&Ksh[rK * 64 + sB];
      const short8 kl0 = *(const short8*)&Ksl[rK * 64 + sA];
      const short8 kl1 = *(const short8*)&Ksl[rK * 64 + sB];
      f4 s = {0.f, 0.f, 0.f, 0.f};
      s = __builtin_amdgcn_mfma_f32_16x16x32_bf16(qh0, kh0, s, 0, 0, 0);
      s = __builtin_amdgcn_mfma_f32_16x16x32_bf16(qh1, kh1, s, 0, 0, 0);
      s = __builtin_amdgcn_mfma_f32_16x16x32_bf16(qh0, kl0, s, 0, 0, 0);
      s = __builtin_amdgcn_mfma_f32_16x16x32_bf16(qh1, kl1, s, 0, 0, 0);
      s = __builtin_amdgcn_mfma_f32_16x16x32_bf16(ql0, kh0, s, 0, 0, 0);
      s = __builtin_amdgcn_mfma_f32_16x16x32_bf16(ql1, kh1, s, 0, 0, 0);
      sacc[sub] = s;
    }
    __syncthreads();  // K tile fully consumed by all waves (V[vb] untouched)
    if (kt < 31) stage(kb + 64, (kt & 1) ^ 1);  // lands during threefry below

    // threefry + sigmoid sample -> swizzled Pm (0x3F80 / 0 bf16 mask)
    // u < p  <=>  m*(1+e) < 2^23, m = (float)((o0^o1)>>9), e = 2^(s*-log2e/8)
#pragma unroll
    for (int sub = 0; sub < 4; ++sub) {
      const int qP = sub * 2 + (c16 >> 3);
#pragma unroll
      for (int rr = 0; rr < 4; ++rr) {
        const uint32_t f = fb + (uint32_t)(rr * 2048) + (uint32_t)(kb + sub * 16);
        uint32_t o0, o1;
        threefry42(0u, f, o0, o1);
        const float m = (float)((o0 ^ o1) >> 9);
        const float e = __builtin_amdgcn_exp2f(sacc[sub][rr] * -0.18033688f);
        const int rP = w * 16 + quad * 4 + rr;
        const int addr = rP * 64 + (((qP + rP) & 7) * 8) + (c16 & 7);
        Pm[addr] = (fmaf(m, e, m) < 8388608.0f) ? 0x3F80u : 0u;
      }
    }

    // O += P.V — P rows wave-private (lgkmcnt orders write->read); V inline
    const int rp = w * 16 + c16;
    const short8 pa0 = *(const short8*)&Pm[rp * 64 + ((quad + rp) & 7) * 8];
    const short8 pa1 = *(const short8*)&Pm[rp * 64 + ((quad + 4 + rp) & 7) * 8];
#pragma unroll
    for (int sub = 0; sub < 4; ++sub) {
      const int rV = sub * 16 + c16;
      const short8 vv0 = *(const short8*)&Vs[vb + rV * 64 + ((quad + rV) & 7) * 8];
      const short8 vv1 = *(const short8*)&Vs[vb + rV * 64 + ((quad + 4 + rV) & 7) * 8];
      oacc[sub] = __builtin_amdgcn_mfma_f32_16x16x32_bf16(pa0, vv0, oacc[sub], 0, 0, 0);
      oacc[sub] = __builtin_amdgcn_mfma_f32_16x16x32_bf16(pa1, vv1, oacc[sub], 0, 0, 0);
    }
  }

  // epilogue: AO[b*2048+s][h*64+d] bf16; C-layout row=quad*4+r (q), col=c16 (d)
  const int b = bh >> 4, hh = bh & 15;
#pragma unroll
  for (int sub = 0; sub < 4; ++sub)
#pragma unroll
    for (int r = 0; r < 4; ++r) {
      const int srow = b * 2048 + q0 + w * 16 + quad * 4 + r;
      AO[(size_t)srow * 1024 + hh * 64 + sub * 16 + c16] = bf16_rne(oacc[sub][r]);
    }
}

// ---------------- kernel 3: output projection, 32x32 bf16 MFMA ---------------
// Round-9: double-buffered staging (same pattern as k_qkv). 32KB LDS.
__global__ __launch_bounds__(256) void k_out(
    const unsigned short* __restrict__ A, const unsigned short* __restrict__ Bw,
    const float* __restrict__ out_b, float* __restrict__ out) {
  __shared__ unsigned short SM[16384];  // 32KB: 2 buffers x {As,Bs}
  const int tid = threadIdx.x;
  const int lane = tid & 63, wid = tid >> 6;
  const int wm = wid >> 1, wn = wid & 1;
  const int bn = blockIdx.x, bm = blockIdx.y;
  const int l31 = lane & 31, h = lane >> 5;
  const int ldrow = lane >> 2;
  const int ldk = (((lane & 3) - ((lane >> 3) & 3)) & 3) * 8;
  const int rot = (l31 >> 1) & 3;

  f16v acc[2][2];
#pragma unroll
  for (int a = 0; a < 2; ++a)
#pragma unroll
    for (int b = 0; b < 2; ++b)
      acc[a][b] = (f16v){0.f,0.f,0.f,0.f,0.f,0.f,0.f,0.f,0.f,0.f,0.f,0.f,0.f,0.f,0.f,0.f};

  auto stage = [&](int kt, int buf) {
    const int k0 = kt * 32;
    unsigned short* As = SM + buf * 8192;
#pragma unroll
    for (int r = 0; r < 2; ++r) {
      const int c = wid + r * 4;
      const int grow = c * 16 + ldrow;
      const size_t ao = (size_t)(bm * 128 + grow) * 1024 + k0 + ldk;
      const size_t bo = (size_t)(bn * 128 + grow) * 1024 + k0 + ldk;
      const int lo = c * 512 + lane * 8;
      gl2lds16(A + ao, &As[lo]);
      gl2lds16(Bw + bo, &As[4096 + lo]);
    }
  };

  stage(0, 0);

  for (int kt = 0; kt < 32; ++kt) {
    const int cb = kt & 1;
    __syncthreads();  // drains prefetch of tile kt; buf cb^1 free
    if (kt < 31) stage(kt + 1, cb ^ 1);

    const unsigned short* As = SM + cb * 8192;
    const unsigned short* Bs = As + 4096;
#pragma unroll
    for (int ks = 0; ks < 2; ++ks) {
      const int lc = ks * 2 + h;
      const int pcs = ((lc + rot) & 3) * 8;
      short8 af[2], bf_[2];
#pragma unroll
      for (int t = 0; t < 2; ++t) {
        af[t]  = *(const short8*)&As[(wm * 64 + t * 32 + l31) * 32 + pcs];
        bf_[t] = *(const short8*)&Bs[(wn * 64 + t * 32 + l31) * 32 + pcs];
      }
#pragma unroll
      for (int tm = 0; tm < 2; ++tm)
#pragma unroll
        for (int tn = 0; tn < 2; ++tn)
          acc[tm][tn] = __builtin_amdgcn_mfma_f32_32x32x16_bf16(af[tm], bf_[tn], acc[tm][tn], 0, 0, 0);
    }
  }

#pragma unroll
  for (int tm = 0; tm < 2; ++tm) {
#pragma unroll
    for (int tn = 0; tn < 2; ++tn) {
      const int j = bn * 128 + wn * 64 + tn * 32 + l31;
      const float bias = out_b[j];
#pragma unroll
      for (int a = 0; a < 16; ++a) {
        const int i = bm * 128 + wm * 64 + tm * 32 + (a & 3) + 8 * (a >> 2) + 4 * h;
        out[(size_t)i * 1024 + j] = acc[tm][tn][a] + bias;
      }
    }
  }
}

extern "C" void kernel_launch(void* const* d_in, const int* in_sizes, int n_in,
                              void* d_out, int out_size, void* d_ws, size_t ws_size,
                              hipStream_t stream) {
  const float* x     = (const float*)d_in[0];
  const float* qkv_w = (const float*)d_in[3];
  const float* qkv_b = (const float*)d_in[4];
  const float* out_w = (const float*)d_in[5];
  const float* out_b = (const float*)d_in[6];
  float* out = (float*)d_out;

  // workspace carve (ushorts); AO aliases xh (xh dead after k_qkv)
  unsigned short* xh  = (unsigned short*)d_ws;        // 4194304
  unsigned short* xl  = xh + 4194304;                 // 4194304
  unsigned short* wh  = xl + 4194304;                 // 3145728
  unsigned short* wl  = wh + 3145728;                 // 3145728
  unsigned short* woh = wl + 3145728;                 // 1048576
  unsigned short* Vt  = woh + 1048576;                // 4194304
  unsigned short* Qh  = Vt + 4194304;                 // 4194304
  unsigned short* Ql  = Qh + 4194304;                 // 4194304
  unsigned short* Kh  = Ql + 4194304;                 // 4194304
  unsigned short* Kl  = Kh + 4194304;                 // 4194304
  unsigned short* AO  = xh;                           // alias

  k_split<<<8192, 256, 0, stream>>>(x, qkv_w, out_w, xh, xl, wh, wl, woh);
  k_qkv<<<dim3(24, 32), 256, 0, stream>>>(xh, xl, wh, wl, qkv_b, Qh, Ql, Kh, Kl, Vt);
  k_attn<<<dim3(32, 32), 256, 0, stream>>>(Qh, Ql, Kh, Kl, Vt, AO);
  k_out<<<dim3(8, 32), 256, 0, stream>>>(AO, woh, out_b, out);
}